// Round 17
// baseline (304.294 us; speedup 1.0000x reference)
//
#include <hip/hip_runtime.h>

// Problem constants (fixed by the reference)
#define NN 50000
#define NE 800000
#define ND 16
#define ED 16
#define H  128
#define OD 4
#define KPK 288     // GEMM K: 128 h | 128 hagg | 16 ea_agg | deg | 1 | pad
#define LDAK 296    // LDS row stride (shorts)
#define SLOT 64     // fixed CSR slots per node; P(deg>64) ~ 2e-18 for Poisson(16)

// prologue grid split
#define LIFT_B (NN * H / 256)        // 25000
#define PACK_B (3 * 128 * KPK / 256) // 432
#define ZERO_B ((NN + 255) / 256)    // 196

typedef __bf16 bf16;
typedef __attribute__((ext_vector_type(8))) __bf16 bf16x8;
typedef __attribute__((ext_vector_type(4))) float f32x4;

static __device__ __forceinline__ float bf2f(unsigned short u) {
  return __builtin_bit_cast(float, (unsigned int)u << 16);
}
static __device__ __forceinline__ unsigned short f2bfu(float f) {
  return __builtin_bit_cast(unsigned short, (bf16)f);
}
static __device__ __forceinline__ unsigned int pk2(float a, float b) {
  return (unsigned int)f2bfu(a) | ((unsigned int)f2bfu(b) << 16);
}

// ---------------------------------------------------------------------------
// Fused prologue: [0,LIFT_B): lift | [LIFT_B,+PACK_B): pack_w | rest: zero
// ---------------------------------------------------------------------------
__global__ __launch_bounds__(256) void prologue_kernel(
    const float* __restrict__ x, const float* __restrict__ lw,
    const float* __restrict__ lb, bf16* __restrict__ h,
    const float* __restrict__ msg_w, const float* __restrict__ root_w,
    const float* __restrict__ root_b, const float* __restrict__ msg_b,
    bf16* __restrict__ Wp, int* __restrict__ cursor) {
  int bid = blockIdx.x;
  if (bid < LIFT_B) {
    int idx = bid * 256 + threadIdx.x;        // NN*128 exact
    int n = idx >> 7, k = idx & 127;
    float acc = lb[k];
    const float* xr = x + (size_t)n * ND;
#pragma unroll
    for (int j = 0; j < ND; ++j) acc = fmaf(xr[j], lw[j * H + k], acc);
    h[idx] = (bf16)acc;
  } else if (bid < LIFT_B + PACK_B) {
    int idx = (bid - LIFT_B) * 256 + threadIdx.x;  // 3*128*288 exact
    int b = idx / (128 * KPK);
    int r = idx % (128 * KPK);
    int c = r / KPK, k = r % KPK;
    float v = 0.f;
    if (k < 128)       v = root_w[((size_t)b * 128 + k) * 128 + c];
    else if (k < 256)  v = msg_w[((size_t)b * 144 + (k - 128)) * 128 + c];
    else if (k < 272)  v = msg_w[((size_t)b * 144 + 128 + (k - 256)) * 128 + c];
    else if (k == 272) v = msg_b[(size_t)b * 128 + c];
    else if (k == 273) v = root_b[(size_t)b * 128 + c];
    Wp[idx] = (bf16)v;
  } else {
    int i = (bid - LIFT_B - PACK_B) * 256 + threadIdx.x;
    if (i < NN) cursor[i] = 0;
  }
}

// ---------------------------------------------------------------------------
// fill fixed-stride CSR (src,eid) at csr[dst*SLOT + pos], one int2 store.
// XCD-write-partitioned (PART=8). cursor[dst] ends up holding the in-degree.
// ---------------------------------------------------------------------------
__global__ __launch_bounds__(256) void csr_fill_kernel(
    const int* __restrict__ ei, int* __restrict__ cursor,
    int2* __restrict__ csr) {
  int part = blockIdx.x & 7;
  int e0 = (blockIdx.x >> 3) * 1024 + threadIdx.x * 4;
  if (e0 >= NE) return;
  int4 s4 = *(const int4*)&ei[e0];
  int4 d4 = *(const int4*)&ei[NE + e0];
#pragma unroll
  for (int j = 0; j < 4; ++j) {
    int dst = (&d4.x)[j];
    if ((int)(((long long)dst * 8) / NN) == part) {
      int pos = atomicAdd(&cursor[dst], 1);
      if (pos < SLOT)   // statistically never false; memory-safety guard
        csr[dst * SLOT + pos] = make_int2((&s4.x)[j], e0 + j);
    }
  }
}

// ---------------------------------------------------------------------------
// Fused gather + MFMA GEMM (ping-pong h):
//  Phase 1 (per block = 64 nodes): gather hagg into LDS cols [128:256),
//    stage own h rows into [0:128), stat into [256:288).
//    iter==0: also aggregate ea -> stat (write stat to global for reuse)
//    iter>0 : reload stat from global
//  Phase 2: v = A[64x288] @ Wp[288x128] + h (identity)
//    act==1: hout = gelu(v); act==0: out = v @ proj_w + pb (fused projection)
//  hin/hout are DIFFERENT buffers -> no read/write race across blocks.
// ---------------------------------------------------------------------------
__global__ __launch_bounds__(256, 3) void fused_kernel(
    const bf16* __restrict__ hin, bf16* __restrict__ hout,
    const int* __restrict__ cursor, const int2* __restrict__ csr,
    const float* __restrict__ ea, bf16* __restrict__ stat,
    const bf16* __restrict__ Wp, const float* __restrict__ pw,
    const float* __restrict__ pb, float* __restrict__ out,
    int iter, int act) {
  __shared__ bf16 as[64 * LDAK];
  int t = threadIdx.x;
  int lane = t & 63;
  int wv = t >> 6;
  int l15 = lane & 15, g = lane >> 4;
  int c0w = wv * 32;
  int w16 = t >> 4;    // 0..15
  int li = t & 15;
  int m0 = blockIdx.x * 64;

  // persistent B fragments (72 VGPR), L2-hot after first blocks
  bf16x8 bq[9][2];
#pragma unroll
  for (int kk = 0; kk < 9; ++kk)
#pragma unroll
    for (int ni = 0; ni < 2; ++ni)
      bq[kk][ni] = *(const bf16x8*)(Wp + (size_t)(c0w + ni * 16 + l15) * KPK + kk * 32 + g * 8);

  const unsigned short* Hu = (const unsigned short*)hin;
  const unsigned short* S = (const unsigned short*)stat;
  const int* ci = (const int*)csr;
  int k8 = li * 8;

  // ---- Phase 1: stage h rows + gather hagg + stat, 4 nodes per thread ----
  for (int q = 0; q < 4; ++q) {
    int nloc = q * 16 + w16;
    int node = m0 + nloc;
    bool valid = node < NN;
    int deg = valid ? cursor[node] : 0;
    int s = node * SLOT, e = s + deg;

    // stage own h row chunk (cols [0:128))
    uint4 hv = make_uint4(0u, 0u, 0u, 0u);
    if (valid) hv = *(const uint4*)&Hu[(size_t)node * H + k8];
    *(uint4*)(as + nloc * LDAK + k8) = hv;

    float acc[8];
#pragma unroll
    for (int j = 0; j < 8; ++j) acc[j] = 0.f;
    float aea = 0.f;

    int p = s;
    if (iter == 0) {
      for (; p + 4 <= e; p += 4) {
        int s0 = ci[2 * p],     e0 = ci[2 * p + 1];
        int s1 = ci[2 * p + 2], e1 = ci[2 * p + 3];
        int s2 = ci[2 * p + 4], e2 = ci[2 * p + 5];
        int s3 = ci[2 * p + 6], e3 = ci[2 * p + 7];
        uint4 v0 = *(const uint4*)&Hu[(size_t)s0 * H + k8];
        uint4 v1 = *(const uint4*)&Hu[(size_t)s1 * H + k8];
        uint4 v2 = *(const uint4*)&Hu[(size_t)s2 * H + k8];
        uint4 v3 = *(const uint4*)&Hu[(size_t)s3 * H + k8];
        float a0 = ea[(size_t)e0 * ED + li];
        float a1 = ea[(size_t)e1 * ED + li];
        float a2 = ea[(size_t)e2 * ED + li];
        float a3 = ea[(size_t)e3 * ED + li];
#pragma unroll
        for (int j = 0; j < 4; ++j) {
          unsigned int w0 = (&v0.x)[j], w1 = (&v1.x)[j], w2 = (&v2.x)[j], w3 = (&v3.x)[j];
          acc[2 * j]     += (bf2f((unsigned short)(w0 & 0xffff)) + bf2f((unsigned short)(w1 & 0xffff)))
                          + (bf2f((unsigned short)(w2 & 0xffff)) + bf2f((unsigned short)(w3 & 0xffff)));
          acc[2 * j + 1] += (bf2f((unsigned short)(w0 >> 16)) + bf2f((unsigned short)(w1 >> 16)))
                          + (bf2f((unsigned short)(w2 >> 16)) + bf2f((unsigned short)(w3 >> 16)));
        }
        aea += (a0 + a1) + (a2 + a3);
      }
      for (; p < e; ++p) {
        int s0 = ci[2 * p], e0 = ci[2 * p + 1];
        uint4 v0 = *(const uint4*)&Hu[(size_t)s0 * H + k8];
        aea += ea[(size_t)e0 * ED + li];
#pragma unroll
        for (int j = 0; j < 4; ++j) {
          unsigned int w0 = (&v0.x)[j];
          acc[2 * j]     += bf2f((unsigned short)(w0 & 0xffff));
          acc[2 * j + 1] += bf2f((unsigned short)(w0 >> 16));
        }
      }
    } else {
      for (; p + 4 <= e; p += 4) {
        int s0 = ci[2 * p];
        int s1 = ci[2 * p + 2];
        int s2 = ci[2 * p + 4];
        int s3 = ci[2 * p + 6];
        uint4 v0 = *(const uint4*)&Hu[(size_t)s0 * H + k8];
        uint4 v1 = *(const uint4*)&Hu[(size_t)s1 * H + k8];
        uint4 v2 = *(const uint4*)&Hu[(size_t)s2 * H + k8];
        uint4 v3 = *(const uint4*)&Hu[(size_t)s3 * H + k8];
#pragma unroll
        for (int j = 0; j < 4; ++j) {
          unsigned int w0 = (&v0.x)[j], w1 = (&v1.x)[j], w2 = (&v2.x)[j], w3 = (&v3.x)[j];
          acc[2 * j]     += (bf2f((unsigned short)(w0 & 0xffff)) + bf2f((unsigned short)(w1 & 0xffff)))
                          + (bf2f((unsigned short)(w2 & 0xffff)) + bf2f((unsigned short)(w3 & 0xffff)));
          acc[2 * j + 1] += (bf2f((unsigned short)(w0 >> 16)) + bf2f((unsigned short)(w1 >> 16)))
                          + (bf2f((unsigned short)(w2 >> 16)) + bf2f((unsigned short)(w3 >> 16)));
        }
      }
      for (; p < e; ++p) {
        int s0 = ci[2 * p];
        uint4 v0 = *(const uint4*)&Hu[(size_t)s0 * H + k8];
#pragma unroll
        for (int j = 0; j < 4; ++j) {
          unsigned int w0 = (&v0.x)[j];
          acc[2 * j]     += bf2f((unsigned short)(w0 & 0xffff));
          acc[2 * j + 1] += bf2f((unsigned short)(w0 >> 16));
        }
      }
    }

    // hagg -> LDS cols [128:256)
    uint4 o;
    o.x = pk2(acc[0], acc[1]);
    o.y = pk2(acc[2], acc[3]);
    o.z = pk2(acc[4], acc[5]);
    o.w = pk2(acc[6], acc[7]);
    *(uint4*)(as + nloc * LDAK + 128 + k8) = o;

    // stat -> LDS cols [256:288) (+ global persist on iter 0)
    if (iter == 0) {
      unsigned short sv0 = f2bfu(aea);
      unsigned short sv1 = (li == 0) ? f2bfu((float)deg)
                         : (li == 1) ? f2bfu(1.0f) : (unsigned short)0;
      ((unsigned short*)as)[nloc * LDAK + 256 + li] = sv0;
      ((unsigned short*)as)[nloc * LDAK + 272 + li] = sv1;
      if (valid) {
        ((unsigned short*)stat)[(size_t)node * 32 + li] = sv0;
        ((unsigned short*)stat)[(size_t)node * 32 + 16 + li] = sv1;
      }
    } else {
      unsigned short sv0 = 0, sv1 = 0;
      if (valid) {
        sv0 = S[(size_t)node * 32 + li];
        sv1 = S[(size_t)node * 32 + 16 + li];
      }
      ((unsigned short*)as)[nloc * LDAK + 256 + li] = sv0;
      ((unsigned short*)as)[nloc * LDAK + 272 + li] = sv1;
    }
  }
  __syncthreads();

  // ---- Phase 2: MFMA ----
  f32x4 acc[4][2];
#pragma unroll
  for (int mi = 0; mi < 4; ++mi)
#pragma unroll
    for (int ni = 0; ni < 2; ++ni)
      acc[mi][ni] = (f32x4){0.f, 0.f, 0.f, 0.f};

#pragma unroll
  for (int kk = 0; kk < 9; ++kk) {
    bf16x8 af[4];
#pragma unroll
    for (int mi = 0; mi < 4; ++mi)
      af[mi] = *(const bf16x8*)(as + (mi * 16 + l15) * LDAK + kk * 32 + g * 8);
#pragma unroll
    for (int mi = 0; mi < 4; ++mi)
#pragma unroll
      for (int ni = 0; ni < 2; ++ni)
        acc[mi][ni] = __builtin_amdgcn_mfma_f32_16x16x32_bf16(
            af[mi], bq[kk][ni], acc[mi][ni], 0, 0, 0);
  }

  if (act) {
#pragma unroll
    for (int mi = 0; mi < 4; ++mi) {
#pragma unroll
      for (int ni = 0; ni < 2; ++ni) {
#pragma unroll
        for (int i = 0; i < 4; ++i) {
          int rloc = mi * 16 + g * 4 + i;
          int row = m0 + rloc;
          int col = c0w + ni * 16 + l15;
          if (row < NN) {
            float v = acc[mi][ni][i];
            v += bf2f(__builtin_bit_cast(unsigned short, as[rloc * LDAK + col]));
            float u = 0.7978845608028654f * (v + 0.044715f * v * v * v);
            v = 0.5f * v * (1.f + tanhf(u));
            hout[(size_t)row * H + col] = (bf16)v;
          }
        }
      }
    }
  } else {
    // last block: identity (no gelu), park h_new in LDS, fused projection
    __syncthreads();
#pragma unroll
    for (int mi = 0; mi < 4; ++mi) {
#pragma unroll
      for (int ni = 0; ni < 2; ++ni) {
#pragma unroll
        for (int i = 0; i < 4; ++i) {
          int rloc = mi * 16 + g * 4 + i;
          int col = c0w + ni * 16 + l15;
          float v = acc[mi][ni][i];
          v += bf2f(__builtin_bit_cast(unsigned short, as[rloc * LDAK + col]));
          as[rloc * LDAK + col] = (bf16)v;
        }
      }
    }
    __syncthreads();
    int row = t >> 2, o = t & 3;
    float accp = pb[o];
    const unsigned short* hr = (const unsigned short*)(as + row * LDAK);
#pragma unroll
    for (int j = 0; j < H; ++j)
      accp = fmaf(bf2f(hr[j]), pw[j * OD + o], accp);
    if (m0 + row < NN) out[(size_t)(m0 + row) * OD + o] = accp;
  }
}

extern "C" void kernel_launch(void* const* d_in, const int* in_sizes, int n_in,
                              void* d_out, int out_size, void* d_ws, size_t ws_size,
                              hipStream_t stream) {
  const float* x       = (const float*)d_in[0];
  const int*   ei      = (const int*)d_in[1];
  const float* ea      = (const float*)d_in[2];
  const float* lift_w  = (const float*)d_in[3];
  const float* lift_b  = (const float*)d_in[4];
  const float* root_w  = (const float*)d_in[5];
  const float* root_b  = (const float*)d_in[6];
  const float* msg_w   = (const float*)d_in[7];
  const float* msg_b   = (const float*)d_in[8];
  const float* proj_w  = (const float*)d_in[9];
  const float* proj_b  = (const float*)d_in[10];
  float* out = (float*)d_out;

  char* w = (char*)d_ws;
  bf16*  hA     = (bf16*)w;              w += (size_t)NN * H * 2;        // 12.8 MB
  bf16*  hB     = (bf16*)w;              w += (size_t)NN * H * 2;        // 12.8 MB
  bf16*  stat   = (bf16*)w;              w += (size_t)NN * 32 * 2;       //  3.2 MB
  bf16*  Wp     = (bf16*)w;              w += (size_t)3 * 128 * KPK * 2; // 0.22 MB
  int2*  csr    = (int2*)w;              w += (size_t)NN * SLOT * 8;     // 25.6 MB
  int*   cursor  = (int*)w;

  const int GB = (NN + 63) / 64;  // 782

  prologue_kernel<<<LIFT_B + PACK_B + ZERO_B, 256, 0, stream>>>(
      x, lift_w, lift_b, hA, msg_w, root_w, root_b, msg_b, Wp, cursor);
  csr_fill_kernel<<<8 * ((NE + 1023) / 1024), 256, 0, stream>>>(ei, cursor, csr);

  fused_kernel<<<GB, 256, 0, stream>>>(hA, hB, cursor, csr, ea, stat,
                                       Wp, proj_w, proj_b, out, 0, 1);
  fused_kernel<<<GB, 256, 0, stream>>>(hB, hA, cursor, csr, ea, stat,
                                       Wp + (size_t)128 * KPK, proj_w, proj_b, out, 1, 1);
  fused_kernel<<<GB, 256, 0, stream>>>(hA, hB, cursor, csr, ea, stat,
                                       Wp + (size_t)2 * 128 * KPK, proj_w, proj_b, out, 2, 0);
}

// Round 18
// 277.525 us; speedup vs baseline: 1.0965x; 1.0965x over previous
//
#include <hip/hip_runtime.h>

// Problem constants (fixed by the reference)
#define NN 50000
#define NE 800000
#define ND 16
#define ED 16
#define H  128
#define OD 4
#define KPK 288     // GEMM K: 128 h | 128 hagg | 16 ea_agg | deg | 1 | pad
#define LDAK 296    // LDS row stride (shorts)
#define SLOT 64     // fixed CSR slots per node; P(deg>64) ~ 2e-18 for Poisson(16)
#define TM 32       // gemm rows per block (halved for occupancy/MLP)

// prologue grid split
#define LIFT_B (NN * H / 256)        // 25000
#define PACK_B (3 * 128 * KPK / 256) // 432
#define ZERO_B ((NN + 255) / 256)    // 196

typedef __bf16 bf16;
typedef __attribute__((ext_vector_type(8))) __bf16 bf16x8;
typedef __attribute__((ext_vector_type(4))) float f32x4;

static __device__ __forceinline__ float bf2f(unsigned short u) {
  return __builtin_bit_cast(float, (unsigned int)u << 16);
}
static __device__ __forceinline__ unsigned short f2bfu(float f) {
  return __builtin_bit_cast(unsigned short, (bf16)f);
}
static __device__ __forceinline__ unsigned int pk2(float a, float b) {
  return (unsigned int)f2bfu(a) | ((unsigned int)f2bfu(b) << 16);
}

// ---------------------------------------------------------------------------
// Fused prologue: [0,LIFT_B): lift | [LIFT_B,+PACK_B): pack_w | rest: zero
// ---------------------------------------------------------------------------
__global__ __launch_bounds__(256) void prologue_kernel(
    const float* __restrict__ x, const float* __restrict__ lw,
    const float* __restrict__ lb, bf16* __restrict__ h,
    const float* __restrict__ msg_w, const float* __restrict__ root_w,
    const float* __restrict__ root_b, const float* __restrict__ msg_b,
    bf16* __restrict__ Wp, int* __restrict__ cursor) {
  int bid = blockIdx.x;
  if (bid < LIFT_B) {
    int idx = bid * 256 + threadIdx.x;        // NN*128 exact
    int n = idx >> 7, k = idx & 127;
    float acc = lb[k];
    const float* xr = x + (size_t)n * ND;
#pragma unroll
    for (int j = 0; j < ND; ++j) acc = fmaf(xr[j], lw[j * H + k], acc);
    h[idx] = (bf16)acc;
  } else if (bid < LIFT_B + PACK_B) {
    int idx = (bid - LIFT_B) * 256 + threadIdx.x;  // 3*128*288 exact
    int b = idx / (128 * KPK);
    int r = idx % (128 * KPK);
    int c = r / KPK, k = r % KPK;
    float v = 0.f;
    if (k < 128)       v = root_w[((size_t)b * 128 + k) * 128 + c];
    else if (k < 256)  v = msg_w[((size_t)b * 144 + (k - 128)) * 128 + c];
    else if (k < 272)  v = msg_w[((size_t)b * 144 + 128 + (k - 256)) * 128 + c];
    else if (k == 272) v = msg_b[(size_t)b * 128 + c];
    else if (k == 273) v = root_b[(size_t)b * 128 + c];
    Wp[idx] = (bf16)v;
  } else {
    int i = (bid - LIFT_B - PACK_B) * 256 + threadIdx.x;
    if (i < NN) cursor[i] = 0;
  }
}

// ---------------------------------------------------------------------------
// fill fixed-stride CSR (src,eid) at csr[dst*SLOT + pos], one int2 store.
// XCD-write-partitioned (PART=8). cursor[dst] ends up holding the in-degree.
// ---------------------------------------------------------------------------
__global__ __launch_bounds__(256) void csr_fill_kernel(
    const int* __restrict__ ei, int* __restrict__ cursor,
    int2* __restrict__ csr) {
  int part = blockIdx.x & 7;
  int e0 = (blockIdx.x >> 3) * 1024 + threadIdx.x * 4;
  if (e0 >= NE) return;
  int4 s4 = *(const int4*)&ei[e0];
  int4 d4 = *(const int4*)&ei[NE + e0];
#pragma unroll
  for (int j = 0; j < 4; ++j) {
    int dst = (&d4.x)[j];
    if ((int)(((long long)dst * 8) / NN) == part) {
      int pos = atomicAdd(&cursor[dst], 1);
      if (pos < SLOT)   // statistically never false; memory-safety guard
        csr[dst * SLOT + pos] = make_int2((&s4.x)[j], e0 + j);
    }
  }
}

// ---------------------------------------------------------------------------
// Iter-0 gather, fused with ea aggregation:
//   hagg[i] = sum h[src];  stat[i] = [sum ea[e] | deg | 1 | 0...]
// ---------------------------------------------------------------------------
__global__ __launch_bounds__(256) void gather_ea_kernel(
    const int* __restrict__ cursor, const int2* __restrict__ csr,
    const bf16* __restrict__ h, const float* __restrict__ ea,
    bf16* __restrict__ hagg, bf16* __restrict__ stat) {
  int t = threadIdx.x;
  int node = blockIdx.x * 16 + (t >> 4);   // NN/16 exact
  int li = t & 15;
  int k8 = li * 8;
  int deg = cursor[node];
  int s = node * SLOT, e = s + deg;
  const int* ci = (const int*)csr;
  const unsigned short* Hu = (const unsigned short*)h;

  float acc[8];
#pragma unroll
  for (int j = 0; j < 8; ++j) acc[j] = 0.f;
  float aea = 0.f;

  int p = s;
  for (; p + 4 <= e; p += 4) {
    int s0 = ci[2 * p],     e0 = ci[2 * p + 1];
    int s1 = ci[2 * p + 2], e1 = ci[2 * p + 3];
    int s2 = ci[2 * p + 4], e2 = ci[2 * p + 5];
    int s3 = ci[2 * p + 6], e3 = ci[2 * p + 7];
    uint4 v0 = *(const uint4*)&Hu[(size_t)s0 * H + k8];
    uint4 v1 = *(const uint4*)&Hu[(size_t)s1 * H + k8];
    uint4 v2 = *(const uint4*)&Hu[(size_t)s2 * H + k8];
    uint4 v3 = *(const uint4*)&Hu[(size_t)s3 * H + k8];
    float a0 = ea[(size_t)e0 * ED + li];
    float a1 = ea[(size_t)e1 * ED + li];
    float a2 = ea[(size_t)e2 * ED + li];
    float a3 = ea[(size_t)e3 * ED + li];
#pragma unroll
    for (int j = 0; j < 4; ++j) {
      unsigned int w0 = (&v0.x)[j], w1 = (&v1.x)[j], w2 = (&v2.x)[j], w3 = (&v3.x)[j];
      acc[2 * j]     += (bf2f((unsigned short)(w0 & 0xffff)) + bf2f((unsigned short)(w1 & 0xffff)))
                      + (bf2f((unsigned short)(w2 & 0xffff)) + bf2f((unsigned short)(w3 & 0xffff)));
      acc[2 * j + 1] += (bf2f((unsigned short)(w0 >> 16)) + bf2f((unsigned short)(w1 >> 16)))
                      + (bf2f((unsigned short)(w2 >> 16)) + bf2f((unsigned short)(w3 >> 16)));
    }
    aea += (a0 + a1) + (a2 + a3);
  }
  for (; p < e; ++p) {
    int s0 = ci[2 * p], e0 = ci[2 * p + 1];
    uint4 v0 = *(const uint4*)&Hu[(size_t)s0 * H + k8];
    aea += ea[(size_t)e0 * ED + li];
#pragma unroll
    for (int j = 0; j < 4; ++j) {
      unsigned int w0 = (&v0.x)[j];
      acc[2 * j]     += bf2f((unsigned short)(w0 & 0xffff));
      acc[2 * j + 1] += bf2f((unsigned short)(w0 >> 16));
    }
  }

  uint4 o;
  o.x = pk2(acc[0], acc[1]);
  o.y = pk2(acc[2], acc[3]);
  o.z = pk2(acc[4], acc[5]);
  o.w = pk2(acc[6], acc[7]);
  *(uint4*)&((unsigned short*)hagg)[(size_t)node * H + k8] = o;

  unsigned short* S = (unsigned short*)stat;
  S[(size_t)node * 32 + li] = f2bfu(aea);
  float v2 = (li == 0) ? (float)deg : (li == 1 ? 1.0f : 0.0f);
  S[(size_t)node * 32 + 16 + li] = f2bfu(v2);
}

// ---------------------------------------------------------------------------
// Iters 1-2 gather: hagg[i] = sum h[src]; unroll-4 (R10-proven)
// ---------------------------------------------------------------------------
__global__ __launch_bounds__(256) void gather_h_kernel(
    const int* __restrict__ cursor, const int2* __restrict__ csr,
    const bf16* __restrict__ h, bf16* __restrict__ hagg) {
  int t = threadIdx.x;
  int node = blockIdx.x * 16 + (t >> 4);   // NN/16 exact
  int li = t & 15;
  int k8 = li * 8;
  int deg = cursor[node];
  int s = node * SLOT, e = s + deg;
  const int* ci = (const int*)csr;
  const unsigned short* Hu = (const unsigned short*)h;

  float acc[8];
#pragma unroll
  for (int j = 0; j < 8; ++j) acc[j] = 0.f;

  int p = s;
  for (; p + 4 <= e; p += 4) {
    int s0 = ci[2 * p];
    int s1 = ci[2 * p + 2];
    int s2 = ci[2 * p + 4];
    int s3 = ci[2 * p + 6];
    uint4 v0 = *(const uint4*)&Hu[(size_t)s0 * H + k8];
    uint4 v1 = *(const uint4*)&Hu[(size_t)s1 * H + k8];
    uint4 v2 = *(const uint4*)&Hu[(size_t)s2 * H + k8];
    uint4 v3 = *(const uint4*)&Hu[(size_t)s3 * H + k8];
#pragma unroll
    for (int j = 0; j < 4; ++j) {
      unsigned int w0 = (&v0.x)[j], w1 = (&v1.x)[j], w2 = (&v2.x)[j], w3 = (&v3.x)[j];
      acc[2 * j]     += (bf2f((unsigned short)(w0 & 0xffff)) + bf2f((unsigned short)(w1 & 0xffff)))
                      + (bf2f((unsigned short)(w2 & 0xffff)) + bf2f((unsigned short)(w3 & 0xffff)));
      acc[2 * j + 1] += (bf2f((unsigned short)(w0 >> 16)) + bf2f((unsigned short)(w1 >> 16)))
                      + (bf2f((unsigned short)(w2 >> 16)) + bf2f((unsigned short)(w3 >> 16)));
    }
  }
  for (; p < e; ++p) {
    int s0 = ci[2 * p];
    uint4 v0 = *(const uint4*)&Hu[(size_t)s0 * H + k8];
#pragma unroll
    for (int j = 0; j < 4; ++j) {
      unsigned int w0 = (&v0.x)[j];
      acc[2 * j]     += bf2f((unsigned short)(w0 & 0xffff));
      acc[2 * j + 1] += bf2f((unsigned short)(w0 >> 16));
    }
  }

  uint4 o;
  o.x = pk2(acc[0], acc[1]);
  o.y = pk2(acc[2], acc[3]);
  o.z = pk2(acc[4], acc[5]);
  o.w = pk2(acc[6], acc[7]);
  *(uint4*)&((unsigned short*)hagg)[(size_t)node * H + k8] = o;
}

// ---------------------------------------------------------------------------
// MFMA GEMM (TM=32 rows/block for occupancy/MLP):
//   v = [h|hagg|stat][32x288] @ Wp[288x128] + h (identity)
//   act==1: h = gelu(v); act==0: out = v @ proj_w + pb (fused projection)
// LDS 18.9KB, VGPR ~84 -> 6 blocks/CU (launch_bounds(256,6) caps VGPR at 85)
// ---------------------------------------------------------------------------
__global__ __launch_bounds__(256, 6) void gemm_mfma_kernel(
    bf16* __restrict__ h, const bf16* __restrict__ hagg,
    const bf16* __restrict__ stat, const bf16* __restrict__ Wp,
    const float* __restrict__ pw, const float* __restrict__ pb,
    float* __restrict__ out, int act) {
  __shared__ bf16 as[TM * LDAK];
  int t = threadIdx.x;
  int lane = t & 63;
  int wv = t >> 6;
  int l15 = lane & 15, g = lane >> 4;
  int c0w = wv * 32;

  bf16x8 bq[9][2];
#pragma unroll
  for (int kk = 0; kk < 9; ++kk)
#pragma unroll
    for (int ni = 0; ni < 2; ++ni)
      bq[kk][ni] = *(const bf16x8*)(Wp + (size_t)(c0w + ni * 16 + l15) * KPK + kk * 32 + g * 8);

  int m0 = blockIdx.x * TM;
  // stage TM rows x (h 16 | hagg 16 | stat 4) 16B-chunks = 1152, 5/thread
#pragma unroll
  for (int i = 0; i < 5; ++i) {
    int idx = i * 256 + t;
    if (idx < TM * 36) {
      int r = idx / 36, seg = idx % 36;
      int node = m0 + r;
      float4 v = make_float4(0.f, 0.f, 0.f, 0.f);
      if (node < NN) {
        const bf16* src;
        if (seg < 16)      src = h    + (size_t)node * H + seg * 8;
        else if (seg < 32) src = hagg + (size_t)node * H + (seg - 16) * 8;
        else               src = stat + (size_t)node * 32 + (seg - 32) * 8;
        v = *(const float4*)src;
      }
      *(float4*)(as + r * LDAK + seg * 8) = v;
    }
  }
  __syncthreads();

  f32x4 acc[2][2];
#pragma unroll
  for (int mi = 0; mi < 2; ++mi)
#pragma unroll
    for (int ni = 0; ni < 2; ++ni)
      acc[mi][ni] = (f32x4){0.f, 0.f, 0.f, 0.f};

#pragma unroll
  for (int kk = 0; kk < 9; ++kk) {
    bf16x8 af[2];
#pragma unroll
    for (int mi = 0; mi < 2; ++mi)
      af[mi] = *(const bf16x8*)(as + (mi * 16 + l15) * LDAK + kk * 32 + g * 8);
#pragma unroll
    for (int mi = 0; mi < 2; ++mi)
#pragma unroll
      for (int ni = 0; ni < 2; ++ni)
        acc[mi][ni] = __builtin_amdgcn_mfma_f32_16x16x32_bf16(
            af[mi], bq[kk][ni], acc[mi][ni], 0, 0, 0);
  }

  if (act) {
#pragma unroll
    for (int mi = 0; mi < 2; ++mi) {
#pragma unroll
      for (int ni = 0; ni < 2; ++ni) {
#pragma unroll
        for (int i = 0; i < 4; ++i) {
          int rloc = mi * 16 + g * 4 + i;
          int row = m0 + rloc;
          int col = c0w + ni * 16 + l15;
          if (row < NN) {
            float v = acc[mi][ni][i];
            v += bf2f(__builtin_bit_cast(unsigned short, as[rloc * LDAK + col]));
            float u = 0.7978845608028654f * (v + 0.044715f * v * v * v);
            v = 0.5f * v * (1.f + tanhf(u));
            h[(size_t)row * H + col] = (bf16)v;
          }
        }
      }
    }
  } else {
    // last block: identity (no gelu), park h_new in LDS, fused projection
    __syncthreads();
#pragma unroll
    for (int mi = 0; mi < 2; ++mi) {
#pragma unroll
      for (int ni = 0; ni < 2; ++ni) {
#pragma unroll
        for (int i = 0; i < 4; ++i) {
          int rloc = mi * 16 + g * 4 + i;
          int col = c0w + ni * 16 + l15;
          float v = acc[mi][ni][i];
          v += bf2f(__builtin_bit_cast(unsigned short, as[rloc * LDAK + col]));
          as[rloc * LDAK + col] = (bf16)v;
        }
      }
    }
    __syncthreads();
    if (t < TM * OD) {
      int row = t >> 2, o = t & 3;
      float accp = pb[o];
      const unsigned short* hr = (const unsigned short*)(as + row * LDAK);
#pragma unroll
      for (int j = 0; j < H; ++j)
        accp = fmaf(bf2f(hr[j]), pw[j * OD + o], accp);
      if (m0 + row < NN) out[(size_t)(m0 + row) * OD + o] = accp;
    }
  }
}

extern "C" void kernel_launch(void* const* d_in, const int* in_sizes, int n_in,
                              void* d_out, int out_size, void* d_ws, size_t ws_size,
                              hipStream_t stream) {
  const float* x       = (const float*)d_in[0];
  const int*   ei      = (const int*)d_in[1];
  const float* ea      = (const float*)d_in[2];
  const float* lift_w  = (const float*)d_in[3];
  const float* lift_b  = (const float*)d_in[4];
  const float* root_w  = (const float*)d_in[5];
  const float* root_b  = (const float*)d_in[6];
  const float* msg_w   = (const float*)d_in[7];
  const float* msg_b   = (const float*)d_in[8];
  const float* proj_w  = (const float*)d_in[9];
  const float* proj_b  = (const float*)d_in[10];
  float* out = (float*)d_out;

  char* w = (char*)d_ws;
  bf16*  h      = (bf16*)w;              w += (size_t)NN * H * 2;        // 12.8 MB
  bf16*  hagg   = (bf16*)w;              w += (size_t)NN * H * 2;        // 12.8 MB
  bf16*  stat   = (bf16*)w;              w += (size_t)NN * 32 * 2;       //  3.2 MB
  bf16*  Wp     = (bf16*)w;              w += (size_t)3 * 128 * KPK * 2; // 0.22 MB
  int2*  csr    = (int2*)w;              w += (size_t)NN * SLOT * 8;     // 25.6 MB
  int*   cursor  = (int*)w;

  prologue_kernel<<<LIFT_B + PACK_B + ZERO_B, 256, 0, stream>>>(
      x, lift_w, lift_b, h, msg_w, root_w, root_b, msg_b, Wp, cursor);
  csr_fill_kernel<<<8 * ((NE + 1023) / 1024), 256, 0, stream>>>(ei, cursor, csr);

  for (int b = 0; b < 3; ++b) {
    if (b == 0)
      gather_ea_kernel<<<NN / 16, 256, 0, stream>>>(cursor, csr, h, ea, hagg, stat);
    else
      gather_h_kernel<<<NN / 16, 256, 0, stream>>>(cursor, csr, h, hagg);
    gemm_mfma_kernel<<<(NN + TM - 1) / TM, 256, 0, stream>>>(
        h, hagg, stat, Wp + (size_t)b * 128 * KPK,
        proj_w, proj_b, out, b < 2 ? 1 : 0);
  }
}

// Round 19
// 257.679 us; speedup vs baseline: 1.1809x; 1.0770x over previous
//
#include <hip/hip_runtime.h>

// Problem constants (fixed by the reference)
#define NN 50000
#define NE 800000
#define ND 16
#define ED 16
#define H  128
#define OD 4
#define KPK 288     // GEMM K: 128 h | 128 hagg | 16 ea_agg | deg | 1 | pad
#define LDAK 296    // LDS row stride (shorts)
#define SLOT 64     // fixed CSR slots per node; P(deg>64) ~ 2e-18 for Poisson(16)
#define TM 32       // gemm rows per block (occupancy/MLP; default launch bounds!)

// prologue grid split
#define LIFT_B (NN * H / 256)        // 25000
#define PACK_B (3 * 128 * KPK / 256) // 432
#define ZERO_B ((NN + 255) / 256)    // 196

typedef __bf16 bf16;
typedef __attribute__((ext_vector_type(8))) __bf16 bf16x8;
typedef __attribute__((ext_vector_type(4))) float f32x4;

static __device__ __forceinline__ float bf2f(unsigned short u) {
  return __builtin_bit_cast(float, (unsigned int)u << 16);
}
static __device__ __forceinline__ unsigned short f2bfu(float f) {
  return __builtin_bit_cast(unsigned short, (bf16)f);
}
static __device__ __forceinline__ unsigned int pk2(float a, float b) {
  return (unsigned int)f2bfu(a) | ((unsigned int)f2bfu(b) << 16);
}

// ---------------------------------------------------------------------------
// Fused prologue: [0,LIFT_B): lift | [LIFT_B,+PACK_B): pack_w | rest: zero
// ---------------------------------------------------------------------------
__global__ __launch_bounds__(256) void prologue_kernel(
    const float* __restrict__ x, const float* __restrict__ lw,
    const float* __restrict__ lb, bf16* __restrict__ h,
    const float* __restrict__ msg_w, const float* __restrict__ root_w,
    const float* __restrict__ root_b, const float* __restrict__ msg_b,
    bf16* __restrict__ Wp, int* __restrict__ cursor) {
  int bid = blockIdx.x;
  if (bid < LIFT_B) {
    int idx = bid * 256 + threadIdx.x;        // NN*128 exact
    int n = idx >> 7, k = idx & 127;
    float acc = lb[k];
    const float* xr = x + (size_t)n * ND;
#pragma unroll
    for (int j = 0; j < ND; ++j) acc = fmaf(xr[j], lw[j * H + k], acc);
    h[idx] = (bf16)acc;
  } else if (bid < LIFT_B + PACK_B) {
    int idx = (bid - LIFT_B) * 256 + threadIdx.x;  // 3*128*288 exact
    int b = idx / (128 * KPK);
    int r = idx % (128 * KPK);
    int c = r / KPK, k = r % KPK;
    float v = 0.f;
    if (k < 128)       v = root_w[((size_t)b * 128 + k) * 128 + c];
    else if (k < 256)  v = msg_w[((size_t)b * 144 + (k - 128)) * 128 + c];
    else if (k < 272)  v = msg_w[((size_t)b * 144 + 128 + (k - 256)) * 128 + c];
    else if (k == 272) v = msg_b[(size_t)b * 128 + c];
    else if (k == 273) v = root_b[(size_t)b * 128 + c];
    Wp[idx] = (bf16)v;
  } else {
    int i = (bid - LIFT_B - PACK_B) * 256 + threadIdx.x;
    if (i < NN) cursor[i] = 0;
  }
}

// ---------------------------------------------------------------------------
// fill fixed-stride CSR (src,eid) at csr[dst*SLOT + pos], one int2 store.
// XCD-write-partitioned (PART=8). cursor[dst] ends up holding the in-degree.
// ---------------------------------------------------------------------------
__global__ __launch_bounds__(256) void csr_fill_kernel(
    const int* __restrict__ ei, int* __restrict__ cursor,
    int2* __restrict__ csr) {
  int part = blockIdx.x & 7;
  int e0 = (blockIdx.x >> 3) * 1024 + threadIdx.x * 4;
  if (e0 >= NE) return;
  int4 s4 = *(const int4*)&ei[e0];
  int4 d4 = *(const int4*)&ei[NE + e0];
#pragma unroll
  for (int j = 0; j < 4; ++j) {
    int dst = (&d4.x)[j];
    if ((int)(((long long)dst * 8) / NN) == part) {
      int pos = atomicAdd(&cursor[dst], 1);
      if (pos < SLOT)   // statistically never false; memory-safety guard
        csr[dst * SLOT + pos] = make_int2((&s4.x)[j], e0 + j);
    }
  }
}

// ---------------------------------------------------------------------------
// Iter-0 gather, fused with ea aggregation:
//   hagg[i] = sum h[src];  stat[i] = [sum ea[e] | deg | 1 | 0...]
// ---------------------------------------------------------------------------
__global__ __launch_bounds__(256) void gather_ea_kernel(
    const int* __restrict__ cursor, const int2* __restrict__ csr,
    const bf16* __restrict__ h, const float* __restrict__ ea,
    bf16* __restrict__ hagg, bf16* __restrict__ stat) {
  int t = threadIdx.x;
  int node = blockIdx.x * 16 + (t >> 4);   // NN/16 exact
  int li = t & 15;
  int k8 = li * 8;
  int deg = cursor[node];
  int s = node * SLOT, e = s + deg;
  const int* ci = (const int*)csr;
  const unsigned short* Hu = (const unsigned short*)h;

  float acc[8];
#pragma unroll
  for (int j = 0; j < 8; ++j) acc[j] = 0.f;
  float aea = 0.f;

  int p = s;
  for (; p + 4 <= e; p += 4) {
    int s0 = ci[2 * p],     e0 = ci[2 * p + 1];
    int s1 = ci[2 * p + 2], e1 = ci[2 * p + 3];
    int s2 = ci[2 * p + 4], e2 = ci[2 * p + 5];
    int s3 = ci[2 * p + 6], e3 = ci[2 * p + 7];
    uint4 v0 = *(const uint4*)&Hu[(size_t)s0 * H + k8];
    uint4 v1 = *(const uint4*)&Hu[(size_t)s1 * H + k8];
    uint4 v2 = *(const uint4*)&Hu[(size_t)s2 * H + k8];
    uint4 v3 = *(const uint4*)&Hu[(size_t)s3 * H + k8];
    float a0 = ea[(size_t)e0 * ED + li];
    float a1 = ea[(size_t)e1 * ED + li];
    float a2 = ea[(size_t)e2 * ED + li];
    float a3 = ea[(size_t)e3 * ED + li];
#pragma unroll
    for (int j = 0; j < 4; ++j) {
      unsigned int w0 = (&v0.x)[j], w1 = (&v1.x)[j], w2 = (&v2.x)[j], w3 = (&v3.x)[j];
      acc[2 * j]     += (bf2f((unsigned short)(w0 & 0xffff)) + bf2f((unsigned short)(w1 & 0xffff)))
                      + (bf2f((unsigned short)(w2 & 0xffff)) + bf2f((unsigned short)(w3 & 0xffff)));
      acc[2 * j + 1] += (bf2f((unsigned short)(w0 >> 16)) + bf2f((unsigned short)(w1 >> 16)))
                      + (bf2f((unsigned short)(w2 >> 16)) + bf2f((unsigned short)(w3 >> 16)));
    }
    aea += (a0 + a1) + (a2 + a3);
  }
  for (; p < e; ++p) {
    int s0 = ci[2 * p], e0 = ci[2 * p + 1];
    uint4 v0 = *(const uint4*)&Hu[(size_t)s0 * H + k8];
    aea += ea[(size_t)e0 * ED + li];
#pragma unroll
    for (int j = 0; j < 4; ++j) {
      unsigned int w0 = (&v0.x)[j];
      acc[2 * j]     += bf2f((unsigned short)(w0 & 0xffff));
      acc[2 * j + 1] += bf2f((unsigned short)(w0 >> 16));
    }
  }

  uint4 o;
  o.x = pk2(acc[0], acc[1]);
  o.y = pk2(acc[2], acc[3]);
  o.z = pk2(acc[4], acc[5]);
  o.w = pk2(acc[6], acc[7]);
  *(uint4*)&((unsigned short*)hagg)[(size_t)node * H + k8] = o;

  unsigned short* S = (unsigned short*)stat;
  S[(size_t)node * 32 + li] = f2bfu(aea);
  float v2 = (li == 0) ? (float)deg : (li == 1 ? 1.0f : 0.0f);
  S[(size_t)node * 32 + 16 + li] = f2bfu(v2);
}

// ---------------------------------------------------------------------------
// Iters 1-2 gather: hagg[i] = sum h[src]; unroll-4 (R10-proven)
// ---------------------------------------------------------------------------
__global__ __launch_bounds__(256) void gather_h_kernel(
    const int* __restrict__ cursor, const int2* __restrict__ csr,
    const bf16* __restrict__ h, bf16* __restrict__ hagg) {
  int t = threadIdx.x;
  int node = blockIdx.x * 16 + (t >> 4);   // NN/16 exact
  int li = t & 15;
  int k8 = li * 8;
  int deg = cursor[node];
  int s = node * SLOT, e = s + deg;
  const int* ci = (const int*)csr;
  const unsigned short* Hu = (const unsigned short*)h;

  float acc[8];
#pragma unroll
  for (int j = 0; j < 8; ++j) acc[j] = 0.f;

  int p = s;
  for (; p + 4 <= e; p += 4) {
    int s0 = ci[2 * p];
    int s1 = ci[2 * p + 2];
    int s2 = ci[2 * p + 4];
    int s3 = ci[2 * p + 6];
    uint4 v0 = *(const uint4*)&Hu[(size_t)s0 * H + k8];
    uint4 v1 = *(const uint4*)&Hu[(size_t)s1 * H + k8];
    uint4 v2 = *(const uint4*)&Hu[(size_t)s2 * H + k8];
    uint4 v3 = *(const uint4*)&Hu[(size_t)s3 * H + k8];
#pragma unroll
    for (int j = 0; j < 4; ++j) {
      unsigned int w0 = (&v0.x)[j], w1 = (&v1.x)[j], w2 = (&v2.x)[j], w3 = (&v3.x)[j];
      acc[2 * j]     += (bf2f((unsigned short)(w0 & 0xffff)) + bf2f((unsigned short)(w1 & 0xffff)))
                      + (bf2f((unsigned short)(w2 & 0xffff)) + bf2f((unsigned short)(w3 & 0xffff)));
      acc[2 * j + 1] += (bf2f((unsigned short)(w0 >> 16)) + bf2f((unsigned short)(w1 >> 16)))
                      + (bf2f((unsigned short)(w2 >> 16)) + bf2f((unsigned short)(w3 >> 16)));
    }
  }
  for (; p < e; ++p) {
    int s0 = ci[2 * p];
    uint4 v0 = *(const uint4*)&Hu[(size_t)s0 * H + k8];
#pragma unroll
    for (int j = 0; j < 4; ++j) {
      unsigned int w0 = (&v0.x)[j];
      acc[2 * j]     += bf2f((unsigned short)(w0 & 0xffff));
      acc[2 * j + 1] += bf2f((unsigned short)(w0 >> 16));
    }
  }

  uint4 o;
  o.x = pk2(acc[0], acc[1]);
  o.y = pk2(acc[2], acc[3]);
  o.z = pk2(acc[4], acc[5]);
  o.w = pk2(acc[6], acc[7]);
  *(uint4*)&((unsigned short*)hagg)[(size_t)node * H + k8] = o;
}

// ---------------------------------------------------------------------------
// MFMA GEMM (TM=32, DEFAULT launch bounds — no VGPR cap, no spill):
//   v = [h|hagg|stat][32x288] @ Wp[288x128] + h (identity)
//   act==1: h = gelu(v); act==0: out = v @ proj_w + pb (fused projection)
// LDS 18.9KB; natural VGPR ~110-120 -> ~4 blocks/CU (vs 2-3 at TM=64)
// ---------------------------------------------------------------------------
__global__ __launch_bounds__(256) void gemm_mfma_kernel(
    bf16* __restrict__ h, const bf16* __restrict__ hagg,
    const bf16* __restrict__ stat, const bf16* __restrict__ Wp,
    const float* __restrict__ pw, const float* __restrict__ pb,
    float* __restrict__ out, int act) {
  __shared__ bf16 as[TM * LDAK];
  int t = threadIdx.x;
  int lane = t & 63;
  int wv = t >> 6;
  int l15 = lane & 15, g = lane >> 4;
  int c0w = wv * 32;

  bf16x8 bq[9][2];
#pragma unroll
  for (int kk = 0; kk < 9; ++kk)
#pragma unroll
    for (int ni = 0; ni < 2; ++ni)
      bq[kk][ni] = *(const bf16x8*)(Wp + (size_t)(c0w + ni * 16 + l15) * KPK + kk * 32 + g * 8);

  int m0 = blockIdx.x * TM;
  // stage TM rows x (h 16 | hagg 16 | stat 4) 16B-chunks = 1152, 5/thread
#pragma unroll
  for (int i = 0; i < 5; ++i) {
    int idx = i * 256 + t;
    if (idx < TM * 36) {
      int r = idx / 36, seg = idx % 36;
      int node = m0 + r;
      float4 v = make_float4(0.f, 0.f, 0.f, 0.f);
      if (node < NN) {
        const bf16* src;
        if (seg < 16)      src = h    + (size_t)node * H + seg * 8;
        else if (seg < 32) src = hagg + (size_t)node * H + (seg - 16) * 8;
        else               src = stat + (size_t)node * 32 + (seg - 32) * 8;
        v = *(const float4*)src;
      }
      *(float4*)(as + r * LDAK + seg * 8) = v;
    }
  }
  __syncthreads();

  f32x4 acc[2][2];
#pragma unroll
  for (int mi = 0; mi < 2; ++mi)
#pragma unroll
    for (int ni = 0; ni < 2; ++ni)
      acc[mi][ni] = (f32x4){0.f, 0.f, 0.f, 0.f};

#pragma unroll
  for (int kk = 0; kk < 9; ++kk) {
    bf16x8 af[2];
#pragma unroll
    for (int mi = 0; mi < 2; ++mi)
      af[mi] = *(const bf16x8*)(as + (mi * 16 + l15) * LDAK + kk * 32 + g * 8);
#pragma unroll
    for (int mi = 0; mi < 2; ++mi)
#pragma unroll
      for (int ni = 0; ni < 2; ++ni)
        acc[mi][ni] = __builtin_amdgcn_mfma_f32_16x16x32_bf16(
            af[mi], bq[kk][ni], acc[mi][ni], 0, 0, 0);
  }

  if (act) {
#pragma unroll
    for (int mi = 0; mi < 2; ++mi) {
#pragma unroll
      for (int ni = 0; ni < 2; ++ni) {
#pragma unroll
        for (int i = 0; i < 4; ++i) {
          int rloc = mi * 16 + g * 4 + i;
          int row = m0 + rloc;
          int col = c0w + ni * 16 + l15;
          if (row < NN) {
            float v = acc[mi][ni][i];
            v += bf2f(__builtin_bit_cast(unsigned short, as[rloc * LDAK + col]));
            float u = 0.7978845608028654f * (v + 0.044715f * v * v * v);
            v = 0.5f * v * (1.f + tanhf(u));
            h[(size_t)row * H + col] = (bf16)v;
          }
        }
      }
    }
  } else {
    // last block: identity (no gelu), park h_new in LDS, fused projection
    __syncthreads();
#pragma unroll
    for (int mi = 0; mi < 2; ++mi) {
#pragma unroll
      for (int ni = 0; ni < 2; ++ni) {
#pragma unroll
        for (int i = 0; i < 4; ++i) {
          int rloc = mi * 16 + g * 4 + i;
          int col = c0w + ni * 16 + l15;
          float v = acc[mi][ni][i];
          v += bf2f(__builtin_bit_cast(unsigned short, as[rloc * LDAK + col]));
          as[rloc * LDAK + col] = (bf16)v;
        }
      }
    }
    __syncthreads();
    if (t < TM * OD) {
      int row = t >> 2, o = t & 3;
      float accp = pb[o];
      const unsigned short* hr = (const unsigned short*)(as + row * LDAK);
#pragma unroll
      for (int j = 0; j < H; ++j)
        accp = fmaf(bf2f(hr[j]), pw[j * OD + o], accp);
      if (m0 + row < NN) out[(size_t)(m0 + row) * OD + o] = accp;
    }
  }
}

extern "C" void kernel_launch(void* const* d_in, const int* in_sizes, int n_in,
                              void* d_out, int out_size, void* d_ws, size_t ws_size,
                              hipStream_t stream) {
  const float* x       = (const float*)d_in[0];
  const int*   ei      = (const int*)d_in[1];
  const float* ea      = (const float*)d_in[2];
  const float* lift_w  = (const float*)d_in[3];
  const float* lift_b  = (const float*)d_in[4];
  const float* root_w  = (const float*)d_in[5];
  const float* root_b  = (const float*)d_in[6];
  const float* msg_w   = (const float*)d_in[7];
  const float* msg_b   = (const float*)d_in[8];
  const float* proj_w  = (const float*)d_in[9];
  const float* proj_b  = (const float*)d_in[10];
  float* out = (float*)d_out;

  char* w = (char*)d_ws;
  bf16*  h      = (bf16*)w;              w += (size_t)NN * H * 2;        // 12.8 MB
  bf16*  hagg   = (bf16*)w;              w += (size_t)NN * H * 2;        // 12.8 MB
  bf16*  stat   = (bf16*)w;              w += (size_t)NN * 32 * 2;       //  3.2 MB
  bf16*  Wp     = (bf16*)w;              w += (size_t)3 * 128 * KPK * 2; // 0.22 MB
  int2*  csr    = (int2*)w;              w += (size_t)NN * SLOT * 8;     // 25.6 MB
  int*   cursor  = (int*)w;

  prologue_kernel<<<LIFT_B + PACK_B + ZERO_B, 256, 0, stream>>>(
      x, lift_w, lift_b, h, msg_w, root_w, root_b, msg_b, Wp, cursor);
  csr_fill_kernel<<<8 * ((NE + 1023) / 1024), 256, 0, stream>>>(ei, cursor, csr);

  for (int b = 0; b < 3; ++b) {
    if (b == 0)
      gather_ea_kernel<<<NN / 16, 256, 0, stream>>>(cursor, csr, h, ea, hagg, stat);
    else
      gather_h_kernel<<<NN / 16, 256, 0, stream>>>(cursor, csr, h, hagg);
    gemm_mfma_kernel<<<(NN + TM - 1) / TM, 256, 0, stream>>>(
        h, hagg, stat, Wp + (size_t)b * 128 * KPK,
        proj_w, proj_b, out, b < 2 ? 1 : 0);
  }
}

// Round 20
// 246.999 us; speedup vs baseline: 1.2320x; 1.0432x over previous
//
#include <hip/hip_runtime.h>

// Problem constants (fixed by the reference)
#define NN 50000
#define NE 800000
#define ND 16
#define ED 16
#define H  128
#define OD 4
#define KPK 288     // GEMM K: 128 h | 128 hagg | 16 ea_agg | deg | 1 | pad
#define LDAK 296    // LDS row stride (shorts)
#define SLOT 64     // fixed CSR slots per node; P(deg>64) ~ 2e-18 for Poisson(16)

// prologue grid split
#define LIFT_B (NN * H / 256)        // 25000
#define PACK_B (3 * 128 * KPK / 256) // 432
#define ZERO_B ((NN + 255) / 256)    // 196

typedef __bf16 bf16;
typedef __attribute__((ext_vector_type(8))) __bf16 bf16x8;
typedef __attribute__((ext_vector_type(4))) float f32x4;

static __device__ __forceinline__ float bf2f(unsigned short u) {
  return __builtin_bit_cast(float, (unsigned int)u << 16);
}
static __device__ __forceinline__ unsigned short f2bfu(float f) {
  return __builtin_bit_cast(unsigned short, (bf16)f);
}
static __device__ __forceinline__ unsigned int pk2(float a, float b) {
  return (unsigned int)f2bfu(a) | ((unsigned int)f2bfu(b) << 16);
}

// ---------------------------------------------------------------------------
// Fused prologue: [0,LIFT_B): lift | [LIFT_B,+PACK_B): pack_w | rest: zero
// ---------------------------------------------------------------------------
__global__ __launch_bounds__(256) void prologue_kernel(
    const float* __restrict__ x, const float* __restrict__ lw,
    const float* __restrict__ lb, bf16* __restrict__ h,
    const float* __restrict__ msg_w, const float* __restrict__ root_w,
    const float* __restrict__ root_b, const float* __restrict__ msg_b,
    bf16* __restrict__ Wp, int* __restrict__ cursor) {
  int bid = blockIdx.x;
  if (bid < LIFT_B) {
    int idx = bid * 256 + threadIdx.x;        // NN*128 exact
    int n = idx >> 7, k = idx & 127;
    float acc = lb[k];
    const float* xr = x + (size_t)n * ND;
#pragma unroll
    for (int j = 0; j < ND; ++j) acc = fmaf(xr[j], lw[j * H + k], acc);
    h[idx] = (bf16)acc;
  } else if (bid < LIFT_B + PACK_B) {
    int idx = (bid - LIFT_B) * 256 + threadIdx.x;  // 3*128*288 exact
    int b = idx / (128 * KPK);
    int r = idx % (128 * KPK);
    int c = r / KPK, k = r % KPK;
    float v = 0.f;
    if (k < 128)       v = root_w[((size_t)b * 128 + k) * 128 + c];
    else if (k < 256)  v = msg_w[((size_t)b * 144 + (k - 128)) * 128 + c];
    else if (k < 272)  v = msg_w[((size_t)b * 144 + 128 + (k - 256)) * 128 + c];
    else if (k == 272) v = msg_b[(size_t)b * 128 + c];
    else if (k == 273) v = root_b[(size_t)b * 128 + c];
    Wp[idx] = (bf16)v;
  } else {
    int i = (bid - LIFT_B - PACK_B) * 256 + threadIdx.x;
    if (i < NN) cursor[i] = 0;
  }
}

// ---------------------------------------------------------------------------
// fill fixed-stride CSR (src,eid) at csr[dst*SLOT + pos], one int2 store.
// XCD-write-partitioned (PART=8). cursor[dst] ends up holding the in-degree.
// ---------------------------------------------------------------------------
__global__ __launch_bounds__(256) void csr_fill_kernel(
    const int* __restrict__ ei, int* __restrict__ cursor,
    int2* __restrict__ csr) {
  int part = blockIdx.x & 7;
  int e0 = (blockIdx.x >> 3) * 1024 + threadIdx.x * 4;
  if (e0 >= NE) return;
  int4 s4 = *(const int4*)&ei[e0];
  int4 d4 = *(const int4*)&ei[NE + e0];
#pragma unroll
  for (int j = 0; j < 4; ++j) {
    int dst = (&d4.x)[j];
    if ((int)(((long long)dst * 8) / NN) == part) {
      int pos = atomicAdd(&cursor[dst], 1);
      if (pos < SLOT)   // statistically never false; memory-safety guard
        csr[dst * SLOT + pos] = make_int2((&s4.x)[j], e0 + j);
    }
  }
}

// ---------------------------------------------------------------------------
// Iter-0 gather, fused with ea aggregation:
//   hagg[i] = sum h[src];  stat[i] = [sum ea[e] | deg | 1 | 0...]
// ---------------------------------------------------------------------------
__global__ __launch_bounds__(256) void gather_ea_kernel(
    const int* __restrict__ cursor, const int2* __restrict__ csr,
    const bf16* __restrict__ h, const float* __restrict__ ea,
    bf16* __restrict__ hagg, bf16* __restrict__ stat) {
  int t = threadIdx.x;
  int node = blockIdx.x * 16 + (t >> 4);   // NN/16 exact
  int li = t & 15;
  int k8 = li * 8;
  int deg = cursor[node];
  int s = node * SLOT, e = s + deg;
  const int* ci = (const int*)csr;
  const unsigned short* Hu = (const unsigned short*)h;

  float acc[8];
#pragma unroll
  for (int j = 0; j < 8; ++j) acc[j] = 0.f;
  float aea = 0.f;

  int p = s;
  for (; p + 4 <= e; p += 4) {
    int s0 = ci[2 * p],     e0 = ci[2 * p + 1];
    int s1 = ci[2 * p + 2], e1 = ci[2 * p + 3];
    int s2 = ci[2 * p + 4], e2 = ci[2 * p + 5];
    int s3 = ci[2 * p + 6], e3 = ci[2 * p + 7];
    uint4 v0 = *(const uint4*)&Hu[(size_t)s0 * H + k8];
    uint4 v1 = *(const uint4*)&Hu[(size_t)s1 * H + k8];
    uint4 v2 = *(const uint4*)&Hu[(size_t)s2 * H + k8];
    uint4 v3 = *(const uint4*)&Hu[(size_t)s3 * H + k8];
    float a0 = ea[(size_t)e0 * ED + li];
    float a1 = ea[(size_t)e1 * ED + li];
    float a2 = ea[(size_t)e2 * ED + li];
    float a3 = ea[(size_t)e3 * ED + li];
#pragma unroll
    for (int j = 0; j < 4; ++j) {
      unsigned int w0 = (&v0.x)[j], w1 = (&v1.x)[j], w2 = (&v2.x)[j], w3 = (&v3.x)[j];
      acc[2 * j]     += (bf2f((unsigned short)(w0 & 0xffff)) + bf2f((unsigned short)(w1 & 0xffff)))
                      + (bf2f((unsigned short)(w2 & 0xffff)) + bf2f((unsigned short)(w3 & 0xffff)));
      acc[2 * j + 1] += (bf2f((unsigned short)(w0 >> 16)) + bf2f((unsigned short)(w1 >> 16)))
                      + (bf2f((unsigned short)(w2 >> 16)) + bf2f((unsigned short)(w3 >> 16)));
    }
    aea += (a0 + a1) + (a2 + a3);
  }
  for (; p < e; ++p) {
    int s0 = ci[2 * p], e0 = ci[2 * p + 1];
    uint4 v0 = *(const uint4*)&Hu[(size_t)s0 * H + k8];
    aea += ea[(size_t)e0 * ED + li];
#pragma unroll
    for (int j = 0; j < 4; ++j) {
      unsigned int w0 = (&v0.x)[j];
      acc[2 * j]     += bf2f((unsigned short)(w0 & 0xffff));
      acc[2 * j + 1] += bf2f((unsigned short)(w0 >> 16));
    }
  }

  uint4 o;
  o.x = pk2(acc[0], acc[1]);
  o.y = pk2(acc[2], acc[3]);
  o.z = pk2(acc[4], acc[5]);
  o.w = pk2(acc[6], acc[7]);
  *(uint4*)&((unsigned short*)hagg)[(size_t)node * H + k8] = o;

  unsigned short* S = (unsigned short*)stat;
  S[(size_t)node * 32 + li] = f2bfu(aea);
  float v2 = (li == 0) ? (float)deg : (li == 1 ? 1.0f : 0.0f);
  S[(size_t)node * 32 + 16 + li] = f2bfu(v2);
}

// ---------------------------------------------------------------------------
// Iters 1-2 gather: hagg[i] = sum h[src]; unroll-4 (R10-proven)
// ---------------------------------------------------------------------------
__global__ __launch_bounds__(256) void gather_h_kernel(
    const int* __restrict__ cursor, const int2* __restrict__ csr,
    const bf16* __restrict__ h, bf16* __restrict__ hagg) {
  int t = threadIdx.x;
  int node = blockIdx.x * 16 + (t >> 4);   // NN/16 exact
  int li = t & 15;
  int k8 = li * 8;
  int deg = cursor[node];
  int s = node * SLOT, e = s + deg;
  const int* ci = (const int*)csr;
  const unsigned short* Hu = (const unsigned short*)h;

  float acc[8];
#pragma unroll
  for (int j = 0; j < 8; ++j) acc[j] = 0.f;

  int p = s;
  for (; p + 4 <= e; p += 4) {
    int s0 = ci[2 * p];
    int s1 = ci[2 * p + 2];
    int s2 = ci[2 * p + 4];
    int s3 = ci[2 * p + 6];
    uint4 v0 = *(const uint4*)&Hu[(size_t)s0 * H + k8];
    uint4 v1 = *(const uint4*)&Hu[(size_t)s1 * H + k8];
    uint4 v2 = *(const uint4*)&Hu[(size_t)s2 * H + k8];
    uint4 v3 = *(const uint4*)&Hu[(size_t)s3 * H + k8];
#pragma unroll
    for (int j = 0; j < 4; ++j) {
      unsigned int w0 = (&v0.x)[j], w1 = (&v1.x)[j], w2 = (&v2.x)[j], w3 = (&v3.x)[j];
      acc[2 * j]     += (bf2f((unsigned short)(w0 & 0xffff)) + bf2f((unsigned short)(w1 & 0xffff)))
                      + (bf2f((unsigned short)(w2 & 0xffff)) + bf2f((unsigned short)(w3 & 0xffff)));
      acc[2 * j + 1] += (bf2f((unsigned short)(w0 >> 16)) + bf2f((unsigned short)(w1 >> 16)))
                      + (bf2f((unsigned short)(w2 >> 16)) + bf2f((unsigned short)(w3 >> 16)));
    }
  }
  for (; p < e; ++p) {
    int s0 = ci[2 * p];
    uint4 v0 = *(const uint4*)&Hu[(size_t)s0 * H + k8];
#pragma unroll
    for (int j = 0; j < 4; ++j) {
      unsigned int w0 = (&v0.x)[j];
      acc[2 * j]     += bf2f((unsigned short)(w0 & 0xffff));
      acc[2 * j + 1] += bf2f((unsigned short)(w0 >> 16));
    }
  }

  uint4 o;
  o.x = pk2(acc[0], acc[1]);
  o.y = pk2(acc[2], acc[3]);
  o.z = pk2(acc[4], acc[5]);
  o.w = pk2(acc[6], acc[7]);
  *(uint4*)&((unsigned short*)hagg)[(size_t)node * H + k8] = o;
}

// ---------------------------------------------------------------------------
// MFMA GEMM (64 rows/block, R16-proven):
//   v = [h|hagg|stat][64x288] @ Wp[288x128] + h (identity)
//   act==1: h = gelu(v); act==0: out = v @ proj_w + pb (fused projection)
// ---------------------------------------------------------------------------
__global__ __launch_bounds__(256, 3) void gemm_mfma_kernel(
    bf16* __restrict__ h, const bf16* __restrict__ hagg,
    const bf16* __restrict__ stat, const bf16* __restrict__ Wp,
    const float* __restrict__ pw, const float* __restrict__ pb,
    float* __restrict__ out, int act) {
  __shared__ bf16 as[64 * LDAK];
  int t = threadIdx.x;
  int lane = t & 63;
  int wv = t >> 6;
  int l15 = lane & 15, g = lane >> 4;
  int c0w = wv * 32;

  bf16x8 bq[9][2];
#pragma unroll
  for (int kk = 0; kk < 9; ++kk)
#pragma unroll
    for (int ni = 0; ni < 2; ++ni)
      bq[kk][ni] = *(const bf16x8*)(Wp + (size_t)(c0w + ni * 16 + l15) * KPK + kk * 32 + g * 8);

  int m0 = blockIdx.x * 64;
  // stage 64 rows x (h 16 | hagg 16 | stat 4) 16B-chunks = 2304, 9 per thread
#pragma unroll
  for (int i = 0; i < 9; ++i) {
    int idx = i * 256 + t;
    int r = idx / 36, seg = idx % 36;
    int node = m0 + r;
    float4 v = make_float4(0.f, 0.f, 0.f, 0.f);
    if (node < NN) {
      const bf16* src;
      if (seg < 16)      src = h    + (size_t)node * H + seg * 8;
      else if (seg < 32) src = hagg + (size_t)node * H + (seg - 16) * 8;
      else               src = stat + (size_t)node * 32 + (seg - 32) * 8;
      v = *(const float4*)src;
    }
    *(float4*)(as + r * LDAK + seg * 8) = v;
  }
  __syncthreads();

  f32x4 acc[4][2];
#pragma unroll
  for (int mi = 0; mi < 4; ++mi)
#pragma unroll
    for (int ni = 0; ni < 2; ++ni)
      acc[mi][ni] = (f32x4){0.f, 0.f, 0.f, 0.f};

#pragma unroll
  for (int kk = 0; kk < 9; ++kk) {
    bf16x8 af[4];
#pragma unroll
    for (int mi = 0; mi < 4; ++mi)
      af[mi] = *(const bf16x8*)(as + (mi * 16 + l15) * LDAK + kk * 32 + g * 8);
#pragma unroll
    for (int mi = 0; mi < 4; ++mi)
#pragma unroll
      for (int ni = 0; ni < 2; ++ni)
        acc[mi][ni] = __builtin_amdgcn_mfma_f32_16x16x32_bf16(
            af[mi], bq[kk][ni], acc[mi][ni], 0, 0, 0);
  }

  if (act) {
#pragma unroll
    for (int mi = 0; mi < 4; ++mi) {
#pragma unroll
      for (int ni = 0; ni < 2; ++ni) {
#pragma unroll
        for (int i = 0; i < 4; ++i) {
          int rloc = mi * 16 + g * 4 + i;
          int row = m0 + rloc;
          int col = c0w + ni * 16 + l15;
          if (row < NN) {
            float v = acc[mi][ni][i];
            v += bf2f(__builtin_bit_cast(unsigned short, as[rloc * LDAK + col]));
            float u = 0.7978845608028654f * (v + 0.044715f * v * v * v);
            v = 0.5f * v * (1.f + tanhf(u));
            h[(size_t)row * H + col] = (bf16)v;
          }
        }
      }
    }
  } else {
    // last block: identity (no gelu), park h_new in LDS, fused projection
    __syncthreads();
#pragma unroll
    for (int mi = 0; mi < 4; ++mi) {
#pragma unroll
      for (int ni = 0; ni < 2; ++ni) {
#pragma unroll
        for (int i = 0; i < 4; ++i) {
          int rloc = mi * 16 + g * 4 + i;
          int col = c0w + ni * 16 + l15;
          float v = acc[mi][ni][i];
          v += bf2f(__builtin_bit_cast(unsigned short, as[rloc * LDAK + col]));
          as[rloc * LDAK + col] = (bf16)v;
        }
      }
    }
    __syncthreads();
    int row = t >> 2, o = t & 3;
    float accp = pb[o];
    const unsigned short* hr = (const unsigned short*)(as + row * LDAK);
#pragma unroll
    for (int j = 0; j < H; ++j)
      accp = fmaf(bf2f(hr[j]), pw[j * OD + o], accp);
    if (m0 + row < NN) out[(size_t)(m0 + row) * OD + o] = accp;
  }
}

extern "C" void kernel_launch(void* const* d_in, const int* in_sizes, int n_in,
                              void* d_out, int out_size, void* d_ws, size_t ws_size,
                              hipStream_t stream) {
  const float* x       = (const float*)d_in[0];
  const int*   ei      = (const int*)d_in[1];
  const float* ea      = (const float*)d_in[2];
  const float* lift_w  = (const float*)d_in[3];
  const float* lift_b  = (const float*)d_in[4];
  const float* root_w  = (const float*)d_in[5];
  const float* root_b  = (const float*)d_in[6];
  const float* msg_w   = (const float*)d_in[7];
  const float* msg_b   = (const float*)d_in[8];
  const float* proj_w  = (const float*)d_in[9];
  const float* proj_b  = (const float*)d_in[10];
  float* out = (float*)d_out;

  char* w = (char*)d_ws;
  bf16*  h      = (bf16*)w;              w += (size_t)NN * H * 2;        // 12.8 MB
  bf16*  hagg   = (bf16*)w;              w += (size_t)NN * H * 2;        // 12.8 MB
  bf16*  stat   = (bf16*)w;              w += (size_t)NN * 32 * 2;       //  3.2 MB
  bf16*  Wp     = (bf16*)w;              w += (size_t)3 * 128 * KPK * 2; // 0.22 MB
  int2*  csr    = (int2*)w;              w += (size_t)NN * SLOT * 8;     // 25.6 MB
  int*   cursor  = (int*)w;

  prologue_kernel<<<LIFT_B + PACK_B + ZERO_B, 256, 0, stream>>>(
      x, lift_w, lift_b, h, msg_w, root_w, root_b, msg_b, Wp, cursor);
  csr_fill_kernel<<<8 * ((NE + 1023) / 1024), 256, 0, stream>>>(ei, cursor, csr);

  for (int b = 0; b < 3; ++b) {
    if (b == 0)
      gather_ea_kernel<<<NN / 16, 256, 0, stream>>>(cursor, csr, h, ea, hagg, stat);
    else
      gather_h_kernel<<<NN / 16, 256, 0, stream>>>(cursor, csr, h, hagg);
    gemm_mfma_kernel<<<(NN + 63) / 64, 256, 0, stream>>>(
        h, hagg, stat, Wp + (size_t)b * 128 * KPK,
        proj_w, proj_b, out, b < 2 ? 1 : 0);
  }
}